// Round 8
// baseline (325.368 us; speedup 1.0000x reference)
//
#include <hip/hip_runtime.h>

#define T_ 512
#define K_ 128
#define L2E 1.4426950408889634f
#define LN2 0.6931471805599453f

typedef _Float16 f16x8 __attribute__((ext_vector_type(8)));
typedef float    f32x4 __attribute__((ext_vector_type(4)));

__device__ __forceinline__ int irl(int v, int lane) {
    return __builtin_amdgcn_readlane(v, lane);
}
__device__ __forceinline__ int pk16(float a, float b) {
    return __builtin_bit_cast(int, __builtin_amdgcn_cvt_pkrtz(a, b));
}

// wave64 max-reduce step via DPP (pure VALU). values >= 0 so 0-fill safe.
#define DPPMAX(m, ctrl)                                                     \
    m = fmaxf(m, __int_as_float(__builtin_amdgcn_update_dpp(                 \
                     0, __float_as_int(m), (ctrl), 0xf, 0xf, true)))

#define MFMA16(a, b, c) __builtin_amdgcn_mfma_f32_16x16x32_f16((a), (b), (c), 0, 0, 0)

// LDS ordering fence: drain DS ops + compiler memory barrier, WITHOUT draining
// vmcnt (keeps the 4-deep global h-prefetch in flight, unlike __syncthreads).
#define LDS_FENCE()                                       \
    asm volatile("s_waitcnt lgkmcnt(0)" ::: "memory");    \
    __builtin_amdgcn_sched_barrier(0)

// Scatter one D-tile to Sls rows via PROBED row indices (layout-proof).
#define SSTORE(mt, av)                                    \
    if (isw) {                                            \
        Sls[16*(mt) + rr0] = av[0];                       \
        Sls[16*(mt) + rr1] = av[1];                       \
        Sls[16*(mt) + rr2] = av[2];                       \
        Sls[16*(mt) + rr3] = av[3];                       \
    }

#define BODY(tt, P, SLOT, SNEXT)                                             \
    {                                                                        \
        const int tc = ((tt) + 4 < len) ? (tt) + 4 : len - 1;                \
        SLOT = hb[(size_t)tc * 64];                                          \
        LDS_FENCE();   /* order: prev wls write -> this read */              \
        const int4* wb = (const int4*)(&wls[P][0]);                          \
        const f16x8 Bf0 = __builtin_bit_cast(f16x8, wb[0 + g]);              \
        const f16x8 Bf1 = __builtin_bit_cast(f16x8, wb[4 + g]);              \
        const f16x8 Bf2 = __builtin_bit_cast(f16x8, wb[8 + g]);              \
        const f16x8 Bf3 = __builtin_bit_cast(f16x8, wb[12 + g]);             \
        f32x4 a0 = MFMA16(Af[0][0], Bf0, Z4);                                \
        f32x4 a1 = MFMA16(Af[1][0], Bf0, Z4);                                \
        f32x4 a2 = MFMA16(Af[2][0], Bf0, Z4);                                \
        f32x4 a3 = MFMA16(Af[3][0], Bf0, Z4);                                \
        f32x4 a4 = MFMA16(Af[4][0], Bf0, Z4);                                \
        f32x4 a5 = MFMA16(Af[5][0], Bf0, Z4);                                \
        f32x4 a6 = MFMA16(Af[6][0], Bf0, Z4);                                \
        f32x4 a7 = MFMA16(Af[7][0], Bf0, Z4);                                \
        a0 = MFMA16(Af[0][1], Bf1, a0);  a1 = MFMA16(Af[1][1], Bf1, a1);     \
        a2 = MFMA16(Af[2][1], Bf1, a2);  a3 = MFMA16(Af[3][1], Bf1, a3);     \
        a4 = MFMA16(Af[4][1], Bf1, a4);  a5 = MFMA16(Af[5][1], Bf1, a5);     \
        a6 = MFMA16(Af[6][1], Bf1, a6);  a7 = MFMA16(Af[7][1], Bf1, a7);     \
        a0 = MFMA16(Af[0][2], Bf2, a0);  a1 = MFMA16(Af[1][2], Bf2, a1);     \
        a2 = MFMA16(Af[2][2], Bf2, a2);  a3 = MFMA16(Af[3][2], Bf2, a3);     \
        a4 = MFMA16(Af[4][2], Bf2, a4);  a5 = MFMA16(Af[5][2], Bf2, a5);     \
        a6 = MFMA16(Af[6][2], Bf2, a6);  a7 = MFMA16(Af[7][2], Bf2, a7);     \
        a0 = MFMA16(Af[0][3], Bf3, a0);  a1 = MFMA16(Af[1][3], Bf3, a1);     \
        a2 = MFMA16(Af[2][3], Bf3, a2);  a3 = MFMA16(Af[3][3], Bf3, a3);     \
        a4 = MFMA16(Af[4][3], Bf3, a4);  a5 = MFMA16(Af[5][3], Bf3, a5);     \
        a6 = MFMA16(Af[6][3], Bf3, a6);  a7 = MFMA16(Af[7][3], Bf3, a7);     \
        SSTORE(0, a0); SSTORE(1, a1); SSTORE(2, a2); SSTORE(3, a3);          \
        SSTORE(4, a4); SSTORE(5, a5); SSTORE(6, a6); SSTORE(7, a7);          \
        LDS_FENCE();   /* order: S writes -> S reads */                      \
        w0 = Sls[2 * l]     * ehc0;                                          \
        w1 = Sls[2 * l + 1] * ehc1;                                          \
        wls[(P) ^ 1][l] = pk16(w0, w1);                                      \
        CM2 += epend;                                                        \
        float m_ = fmaxf(w0, w1);                                            \
        DPPMAX(m_, 0x111); DPPMAX(m_, 0x112); DPPMAX(m_, 0x114);             \
        DPPMAX(m_, 0x118); DPPMAX(m_, 0x142); DPPMAX(m_, 0x143);             \
        const float mg = __int_as_float(irl(__float_as_int(m_), 63));        \
        const int   e_ = (int)(__float_as_uint(mg) >> 23) - 127;             \
        epend = (float)e_;                                                   \
        const float cn = __int_as_float((127 - e_) << 23);                   \
        ehc0 = exp2f(SNEXT.x * L2E) * cn;                                    \
        ehc1 = exp2f(SNEXT.y * L2E) * cn;                                    \
    }

// One wave per batch element. Exponential-space recurrence with lag-1
// exact-pow2 rescale; matvec = 32 x mfma_f32_16x16x32_f16 (E as A-fragments
// in regs, u broadcast into all 16 B-columns -> D valid in every lane).
// D-unpack uses a RUNTIME layout probe (rr/cc), so no fragment-layout
// assumptions remain on the D side; A/B k-maps only need mutual symmetry.
__global__ __launch_bounds__(64)
__attribute__((amdgpu_waves_per_eu(1, 1)))
void crf_fwd(const float* __restrict__ h,
             const float* __restrict__ trans,
             const int* __restrict__ lengths,
             float* __restrict__ out)
{
    const int b   = blockIdx.x;
    const int l   = threadIdx.x;     // 0..63
    const int row = l & 15;
    const int g   = l >> 4;

    __shared__ alignas(16) int   wls[2][64];   // packed f16x2 w, parity dbuf
    __shared__ alignas(16) float Sls[128];     // S f32 scratch

    // ---- one-time: E = exp(trans) as 32 MFMA A-fragments ----
    f16x8 Af[8][4];
#pragma unroll
    for (int mt = 0; mt < 8; ++mt) {
#pragma unroll
        for (int ks = 0; ks < 4; ++ks) {
            const float4* tp =
                (const float4*)(trans + (16 * mt + row) * K_ + 32 * ks + 8 * g);
            const float4 x = tp[0], y = tp[1];
            int4 pk;
            pk.x = pk16(exp2f(x.x * L2E), exp2f(x.y * L2E));
            pk.y = pk16(exp2f(x.z * L2E), exp2f(x.w * L2E));
            pk.z = pk16(exp2f(y.x * L2E), exp2f(y.y * L2E));
            pk.w = pk16(exp2f(y.z * L2E), exp2f(y.w * L2E));
            Af[mt][ks] = __builtin_bit_cast(f16x8, pk);
        }
    }
    const f32x4 Z4 = {0.f, 0.f, 0.f, 0.f};

    // ---- one-time: D-layout probe (data-independent, exact in f16/f32) ----
    // probe1: A = splat(row l&15), B = splat(1/32)  -> D elem = its ROW index
    // probe2: A = splat(1/32), B = splat(row l&15)  -> D elem = its COL label
    int rr0, rr1, rr2, rr3, isw;
    {
        const _Float16 rv = (_Float16)row;
        const _Float16 cs = (_Float16)0.03125f;
        const f16x8 pa = {rv, rv, rv, rv, rv, rv, rv, rv};
        const f16x8 pc = {cs, cs, cs, cs, cs, cs, cs, cs};
        const f32x4 pd = MFMA16(pa, pc, Z4);
        rr0 = (int)(pd[0] + 0.5f);
        rr1 = (int)(pd[1] + 0.5f);
        rr2 = (int)(pd[2] + 0.5f);
        rr3 = (int)(pd[3] + 0.5f);
        const f32x4 qd = MFMA16(pc, pa, Z4);
        isw = ((int)(qd[0] + 0.5f) == 0);   // this lane holds column 0 -> writer
    }

    const int len = lengths[b];
    const float2* hb = (const float2*)(h + (size_t)b * (T_ * K_) + 2 * l);

    // state: w one-hot at START=127 (lane 63 hi half)
    float w0 = 0.0f, w1 = (l == 63) ? 1.0f : 0.0f;
    wls[0][l] = pk16(w0, w1);
    float CM2 = 0.0f, epend = 0.0f;

    float2 s0 = hb[0];
    float2 s1 = hb[(size_t)((1 < len) ? 1 : len - 1) * 64];
    float2 s2 = hb[(size_t)((2 < len) ? 2 : len - 1) * 64];
    float2 s3 = hb[(size_t)((3 < len) ? 3 : len - 1) * 64];
    float ehc0 = exp2f(s0.x * L2E);   // c_0 = 1
    float ehc1 = exp2f(s0.y * L2E);

    int t = 0;
    const int nfull = len & ~3;
    for (; t < nfull; t += 4) {
        BODY(t + 0, 0, s0, s1);
        BODY(t + 1, 1, s1, s2);
        BODY(t + 2, 0, s2, s3);
        BODY(t + 3, 1, s3, s0);
    }
    if (t     < len) BODY(t,     0, s0, s1);
    if (t + 1 < len) BODY(t + 1, 1, s1, s2);
    if (t + 2 < len) BODY(t + 2, 0, s2, s3);

    // ---- out[b] = ln2 * (CM2 + log2( sum_i w[i] * exp(trans[END,i]) )) ----
    const float tEa = exp2f(trans[(K_ - 2) * K_ + 2 * l]     * L2E);
    const float tEb = exp2f(trans[(K_ - 2) * K_ + 2 * l + 1] * L2E);
    float s = w0 * tEa + w1 * tEb;
#pragma unroll
    for (int off = 32; off >= 1; off >>= 1)
        s += __shfl_xor(s, off, 64);
    if (l == 0) out[b] = (CM2 + log2f(s)) * LN2;
}

extern "C" void kernel_launch(void* const* d_in, const int* in_sizes, int n_in,
                              void* d_out, int out_size, void* d_ws, size_t ws_size,
                              hipStream_t stream) {
    const float* h       = (const float*)d_in[0];
    const float* trans   = (const float*)d_in[1];
    const int*   lengths = (const int*)d_in[2];
    float*       out     = (float*)d_out;
    const int B = in_sizes[2];   // 512
    crf_fwd<<<B, 64, 0, stream>>>(h, trans, lengths, out);
}

// Round 9
// 238.195 us; speedup vs baseline: 1.3660x; 1.3660x over previous
//
#include <hip/hip_runtime.h>

#define T_ 512
#define K_ 128
#define L2E 1.4426950408889634f
#define LN2 0.6931471805599453f

typedef _Float16 f16x8 __attribute__((ext_vector_type(8)));
typedef float    f32x4 __attribute__((ext_vector_type(4)));

__device__ __forceinline__ int irl(int v, int lane) {
    return __builtin_amdgcn_readlane(v, lane);
}
__device__ __forceinline__ int pk16(float a, float b) {
    return __builtin_bit_cast(int, __builtin_amdgcn_cvt_pkrtz(a, b));
}

// wave64 max-reduce step via DPP (pure VALU). values >= 0 so 0-fill safe.
#define DPPMAX(m, ctrl)                                                     \
    m = fmaxf(m, __int_as_float(__builtin_amdgcn_update_dpp(                 \
                     0, __float_as_int(m), (ctrl), 0xf, 0xf, true)))

#define MFMA16(a, b, c) __builtin_amdgcn_mfma_f32_16x16x32_f16((a), (b), (c), 0, 0, 0)

// Order prior ds_write (w for this step's B) before the B reads, without
// draining vmcnt (keeps the 4-deep global h prefetch in flight).
#define LDS_FENCE() asm volatile("s_waitcnt lgkmcnt(0)" ::: "memory")

#define BODY(tt, P, SLOT, SNEXT)                                             \
    {                                                                        \
        const int tc = ((tt) + 4 < len) ? (tt) + 4 : len - 1;                \
        SLOT = hb[(size_t)tc * 64];                                          \
        LDS_FENCE();                                                         \
        const int4* wb = (const int4*)(&wls[P][0]);                          \
        const f16x8 Bf0 = __builtin_bit_cast(f16x8, wb[0 + g]);              \
        const f16x8 Bf1 = __builtin_bit_cast(f16x8, wb[4 + g]);              \
        const f16x8 Bf2 = __builtin_bit_cast(f16x8, wb[8 + g]);              \
        const f16x8 Bf3 = __builtin_bit_cast(f16x8, wb[12 + g]);             \
        f32x4 a0 = MFMA16(Af[0][0], Bf0, Z4);                                \
        f32x4 a1 = MFMA16(Af[1][0], Bf0, Z4);                                \
        f32x4 a2 = MFMA16(Af[2][0], Bf0, Z4);                                \
        f32x4 a3 = MFMA16(Af[3][0], Bf0, Z4);                                \
        f32x4 a4 = MFMA16(Af[4][0], Bf0, Z4);                                \
        f32x4 a5 = MFMA16(Af[5][0], Bf0, Z4);                                \
        f32x4 a6 = MFMA16(Af[6][0], Bf0, Z4);                                \
        f32x4 a7 = MFMA16(Af[7][0], Bf0, Z4);                                \
        a0 = MFMA16(Af[0][1], Bf1, a0);  a1 = MFMA16(Af[1][1], Bf1, a1);     \
        a2 = MFMA16(Af[2][1], Bf1, a2);  a3 = MFMA16(Af[3][1], Bf1, a3);     \
        a4 = MFMA16(Af[4][1], Bf1, a4);  a5 = MFMA16(Af[5][1], Bf1, a5);     \
        a6 = MFMA16(Af[6][1], Bf1, a6);  a7 = MFMA16(Af[7][1], Bf1, a7);     \
        a0 = MFMA16(Af[0][2], Bf2, a0);  a1 = MFMA16(Af[1][2], Bf2, a1);     \
        a2 = MFMA16(Af[2][2], Bf2, a2);  a3 = MFMA16(Af[3][2], Bf2, a3);     \
        a4 = MFMA16(Af[4][2], Bf2, a4);  a5 = MFMA16(Af[5][2], Bf2, a5);     \
        a6 = MFMA16(Af[6][2], Bf2, a6);  a7 = MFMA16(Af[7][2], Bf2, a7);     \
        a0 = MFMA16(Af[0][3], Bf3, a0);  a1 = MFMA16(Af[1][3], Bf3, a1);     \
        a2 = MFMA16(Af[2][3], Bf3, a2);  a3 = MFMA16(Af[3][3], Bf3, a3);     \
        a4 = MFMA16(Af[4][3], Bf3, a4);  a5 = MFMA16(Af[5][3], Bf3, a5);     \
        a6 = MFMA16(Af[6][3], Bf3, a6);  a7 = MFMA16(Af[7][3], Bf3, a7);     \
        /* lane-local extraction: S[r0],S[r1] = a_{c>>1}[2(c&1) + {0,1}] */  \
        float p0x = bi ? a0[2] : a0[0], p0y = bi ? a0[3] : a0[1];            \
        float p1x = bi ? a1[2] : a1[0], p1y = bi ? a1[3] : a1[1];            \
        float p2x = bi ? a2[2] : a2[0], p2y = bi ? a2[3] : a2[1];            \
        float p3x = bi ? a3[2] : a3[0], p3y = bi ? a3[3] : a3[1];            \
        float p4x = bi ? a4[2] : a4[0], p4y = bi ? a4[3] : a4[1];            \
        float p5x = bi ? a5[2] : a5[0], p5y = bi ? a5[3] : a5[1];            \
        float p6x = bi ? a6[2] : a6[0], p6y = bi ? a6[3] : a6[1];            \
        float p7x = bi ? a7[2] : a7[0], p7y = bi ? a7[3] : a7[1];            \
        float q0x = m0 ? p1x : p0x, q0y = m0 ? p1y : p0y;                    \
        float q1x = m0 ? p3x : p2x, q1y = m0 ? p3y : p2y;                    \
        float q2x = m0 ? p5x : p4x, q2y = m0 ? p5y : p4y;                    \
        float q3x = m0 ? p7x : p6x, q3y = m0 ? p7y : p6y;                    \
        float r0x = m1 ? q1x : q0x, r0y = m1 ? q1y : q0y;                    \
        float r1x = m1 ? q3x : q2x, r1y = m1 ? q3y : q2y;                    \
        const float S0 = m2 ? r1x : r0x;                                     \
        const float S1 = m2 ? r1y : r0y;                                     \
        w0 = S0 * ehc0;                                                      \
        w1 = S1 * ehc1;                                                      \
        wls[(P) ^ 1][mw] = pk16(w0, w1);                                     \
        CM2 += epend;                                                        \
        float m_ = fmaxf(w0, w1);                                            \
        DPPMAX(m_, 0x111); DPPMAX(m_, 0x112); DPPMAX(m_, 0x114);             \
        DPPMAX(m_, 0x118); DPPMAX(m_, 0x142); DPPMAX(m_, 0x143);             \
        const float mg = __int_as_float(irl(__float_as_int(m_), 63));        \
        const int   e_ = (int)(__float_as_uint(mg) >> 23) - 127;             \
        epend = (float)e_;                                                   \
        const float cn = __int_as_float((127 - e_) << 23);                   \
        ehc0 = exp2f(SNEXT.x * L2E) * cn;                                    \
        ehc1 = exp2f(SNEXT.y * L2E) * cn;                                    \
    }

// One wave per batch element. Exponential-space recurrence, lag-1 exact-pow2
// rescale. Matvec = 32 x mfma_f32_16x16x32_f16, E as A-fragments in regs,
// u splat across all 16 B-columns. Lane OWNERSHIP derived from the D layout:
// lane l (c=l&15, g=l>>4) owns rows r0=16(c>>1)+4g+2(c&1), r1=r0+1 -- a
// bijective cover that is lane-LOCAL in D (a_{c>>1}, elems 2(c&1)..+1, via a
// static cndmask tree). Only LDS per step: 1 ds_write of packed w + 4
// ds_read_b128 of B fragments (one lgkmcnt fence).
__global__ __launch_bounds__(64)
__attribute__((amdgpu_waves_per_eu(1, 1)))
void crf_fwd(const float* __restrict__ h,
             const float* __restrict__ trans,
             const int* __restrict__ lengths,
             float* __restrict__ out)
{
    const int b   = blockIdx.x;
    const int l   = threadIdx.x;     // 0..63
    const int row = l & 15;
    const int g   = l >> 4;
    const int c   = row;
    const bool bi = (c & 1) != 0;    // i-pair bit
    const bool m0 = (c & 2) != 0;    // mt bit0
    const bool m1 = (c & 4) != 0;    // mt bit1
    const bool m2 = (c & 8) != 0;    // mt bit2
    const int r0  = 16 * (c >> 1) + 4 * g + 2 * (c & 1);  // owned row pair
    const int mw  = r0 >> 1;                               // wls dword index

    __shared__ alignas(16) int wls[2][64];   // packed f16x2 w, parity dbuf

    // ---- one-time: E = exp(trans) as 32 MFMA A-fragments ----
    f16x8 Af[8][4];
#pragma unroll
    for (int mt = 0; mt < 8; ++mt) {
#pragma unroll
        for (int ks = 0; ks < 4; ++ks) {
            const float4* tp =
                (const float4*)(trans + (16 * mt + row) * K_ + 32 * ks + 8 * g);
            const float4 x = tp[0], y = tp[1];
            int4 pk;
            pk.x = pk16(exp2f(x.x * L2E), exp2f(x.y * L2E));
            pk.y = pk16(exp2f(x.z * L2E), exp2f(x.w * L2E));
            pk.z = pk16(exp2f(y.x * L2E), exp2f(y.y * L2E));
            pk.w = pk16(exp2f(y.z * L2E), exp2f(y.w * L2E));
            Af[mt][ks] = __builtin_bit_cast(f16x8, pk);
        }
    }
    const f32x4 Z4 = {0.f, 0.f, 0.f, 0.f};

    const int len = lengths[b];
    const float2* hb = (const float2*)(h + (size_t)b * (T_ * K_) + r0);

    // state: w one-hot at START=127 (owned by lane 63: r0=126,r1=127)
    float w0 = 0.0f, w1 = (l == 63) ? 1.0f : 0.0f;
    wls[0][mw] = pk16(w0, w1);
    float CM2 = 0.0f, epend = 0.0f;

    float2 s0 = hb[0];
    float2 s1 = hb[(size_t)((1 < len) ? 1 : len - 1) * 64];
    float2 s2 = hb[(size_t)((2 < len) ? 2 : len - 1) * 64];
    float2 s3 = hb[(size_t)((3 < len) ? 3 : len - 1) * 64];
    float ehc0 = exp2f(s0.x * L2E);   // c_0 = 1
    float ehc1 = exp2f(s0.y * L2E);

    int t = 0;
    const int nfull = len & ~3;
    for (; t < nfull; t += 4) {
        BODY(t + 0, 0, s0, s1);
        BODY(t + 1, 1, s1, s2);
        BODY(t + 2, 0, s2, s3);
        BODY(t + 3, 1, s3, s0);
    }
    if (t     < len) BODY(t,     0, s0, s1);
    if (t + 1 < len) BODY(t + 1, 1, s1, s2);
    if (t + 2 < len) BODY(t + 2, 0, s2, s3);

    // ---- out[b] = ln2 * (CM2 + log2( sum_i w[i] * exp(trans[END,i]) )) ----
    const float tEa = exp2f(trans[(K_ - 2) * K_ + r0]     * L2E);
    const float tEb = exp2f(trans[(K_ - 2) * K_ + r0 + 1] * L2E);
    float s = w0 * tEa + w1 * tEb;
#pragma unroll
    for (int off = 32; off >= 1; off >>= 1)
        s += __shfl_xor(s, off, 64);
    if (l == 0) out[b] = (CM2 + log2f(s)) * LN2;
}

extern "C" void kernel_launch(void* const* d_in, const int* in_sizes, int n_in,
                              void* d_out, int out_size, void* d_ws, size_t ws_size,
                              hipStream_t stream) {
    const float* h       = (const float*)d_in[0];
    const float* trans   = (const float*)d_in[1];
    const int*   lengths = (const int*)d_in[2];
    float*       out     = (float*)d_out;
    const int B = in_sizes[2];   // 512
    crf_fwd<<<B, 64, 0, stream>>>(h, trans, lengths, out);
}